// Round 21
// baseline (75.883 us; speedup 1.0000x reference)
//
#include <hip/hip_runtime.h>

// BinaryConv2dSkip1x1 forward, MI355X — wave-per-rt, row-major dispatch,
// transposed-MFMA epilogue (dwordx4 stores).
// out = RPReLU( conv3x3( sign(x+mb), sf*sign(w), pad=1 ) ) + conv1x1(x, skip_w) + skip_b
//
// Binary conv: sign bits expanded to +/-1 int8 planes in LDS (halo/OOB stored 0
// => exact zero padding), computed with mfma_i32_16x16x64_i8.
// Skip 1x1 conv: bf16 mfma_f32_16x16x32_bf16 over K=64.
// Round-21 (base r20, 73.6us): MFMA operand order SWAPPED (x-frag as A, w-frag
// as B). A/B lane layouts are symmetric for these square shapes (both built
// with the same (idx,k)<->(lane,reg) convention), so registers are unchanged
// and D comes out transposed: col=o, row=px-quad. Each lane then holds 4
// CONSECUTIVE PIXELS of one output channel -> epilogue is 8 global_store_
// dwordx4 per thread instead of 32 scalar dwords, and the RPReLU constants
// load once per kernel (o = w*16+lr is r-invariant) instead of 4x per row.

#define HW (256*256)

typedef __bf16 bf16x8 __attribute__((ext_vector_type(8)));
typedef float  f32x4  __attribute__((ext_vector_type(4)));
typedef int    i32x4  __attribute__((ext_vector_type(4)));

// expand 4 sign bits -> 4 i8 bytes (+1 for bit=0, -1 for bit=1)
__device__ __forceinline__ int expand4(unsigned int nib) {
    unsigned int spread = (nib * 0x00204081u) & 0x01010101u;  // bit i -> byte i LSB
    return (int)(0x01010101u ^ (spread * 0xFEu));             // 0x01 or 0xFF per byte
}

// ---------------- prep kernel: one block, 576 threads (o = tid/9, t = tid%9) ----------
__global__ void bq_prep_kernel(const float* __restrict__ weight,   // [64][64][3][3]
                               const float* __restrict__ pr_bias0,
                               const float* __restrict__ prelu_w,
                               const float* __restrict__ pr_bias1,
                               const float* __restrict__ skip_b,
                               const float* __restrict__ skipw,    // [64][64]
                               unsigned short* __restrict__ abits, // [4rt][64 lane][10] u16
                               unsigned short* __restrict__ swfrag,// [4rt][2p][64 lane][8] bf16
                               float* __restrict__ consg) {        // [64][4]
    __shared__ float sabs_l[576];
    const int tid = threadIdx.x;
    const int o = tid / 9, t = tid % 9;
    const int m = o & 15, rt = o >> 4;
    unsigned short bg[4] = {0, 0, 0, 0};
    float sabs = 0.f;
    for (int ch = 0; ch < 64; ++ch) {
        float wv = weight[(o*64 + ch)*9 + t];
        sabs += fabsf(wv);
        if (wv < 0.f) bg[ch >> 4] |= (unsigned short)(1u << (ch & 15));
    }
    // lane l = m + 16*g holds A[m][k], k = g*16 + j; bit j of abits word = sign
    #pragma unroll
    for (int g = 0; g < 4; ++g)
        abits[(rt*64 + m + 16*g)*10 + t] = bg[g];
    sabs_l[tid] = sabs;
    __syncthreads();
    if (t == 0) {
        float s = 0.f;
        #pragma unroll
        for (int k = 0; k < 9; ++k) s += sabs_l[o*9 + k];
        float sf = s / 576.f;
        consg[o*4 + 0] = sf;
        consg[o*4 + 1] = pr_bias0[o];
        consg[o*4 + 2] = prelu_w[o];
        consg[o*4 + 3] = pr_bias1[o] + skip_b[o];
    }
    if (t == 1) {
        for (int p = 0; p < 2; ++p)
            for (int gg = 0; gg < 4; ++gg)
                for (int i = 0; i < 8; ++i) {
                    float wv = skipw[o*64 + p*32 + gg*8 + i];
                    swfrag[((rt*2 + p)*64 + (m + 16*gg))*8 + i] =
                        __builtin_bit_cast(unsigned short, (__bf16)wv);
                }
    }
}

// ---------------- main kernel: tile 32 px x 4 rows, 256 threads ------------------------
__global__ __launch_bounds__(256, 4)
void bq_main_kernel(const float* __restrict__ x,        // [8][64][256][256]
                    const float* __restrict__ mb,       // [64]
                    const unsigned short* __restrict__ abits_g,
                    const unsigned short* __restrict__ swfrag,
                    const float* __restrict__ consg,
                    float* __restrict__ out) {
    __shared__ __align__(16) char planes[6*4*34*16];        // 13056 B
    __shared__ __align__(16) unsigned short xsl4[4*8*32*8]; // 16384 B [row][slot][px^](8)
    __shared__ __align__(16) unsigned short Abits[4*64*10]; // 5120 B
    __shared__ __align__(16) float cons[64*4];              // 1024 B => 35584 B total

    const int tid = threadIdx.x;
    const int l = tid & 63, w = tid >> 6;   // wave w: loads row w, computes rt=w
    const int pxg = l & 7,  chg = l >> 3;   // 4-px group / 8-ch group
    const int lg = l >> 4,  lr = l & 15;

    // XCD swizzle (r18): one batch image per XCD; within an XCD consecutive
    // launches walk COLUMNS (bxp) fastest -> 8 temporally-adjacent blocks cover
    // contiguous 1KB channel-rows (DRAM page locality; halos L2-hot).
    const int id  = blockIdx.x;                 // 0..4095
    const int vid = (id & 7)*512 + (id >> 3);   // 512 consecutive vids per XCD
    const int bxp = vid & 7;                    // 0..7   (fastest: column strip)
    const int byp = (vid >> 3) & 63;            // 0..63  (4-row strip)
    const int b   = vid >> 9;                   // 0..7   (one image per XCD)

    const int h0 = byp*4 + w, px0 = bxp*32;
    const float* xb = x + (size_t)b * 64 * HW;

    for (int i = tid; i < 1280; i += 256)
        ((unsigned int*)Abits)[i] = ((const unsigned int*)abits_g)[i];
    if (tid < 64) ((f32x4*)cons)[tid] = ((const f32x4*)consg)[tid];

    // Skip-weight fragments for this wave's rt (=w): 2 global 16B loads, hoisted.
    const bf16x8 sa0 = *(const bf16x8*)&swfrag[((w*2 + 0)*64 + l)*8];
    const bf16x8 sa1 = *(const bf16x8*)&swfrag[((w*2 + 1)*64 + l)*8];

    // ---- Halo sign bits EARLY: 76 px x 2 ch-halves = 152 jobs; results = 2 regs.
    int hr = 0, hc = 0;
    bool hinb = false;
    unsigned int hbb0 = 0, hbb1 = 0;
    if (tid < 152) {
        const int idx = tid >> 1, hh = tid & 1;
        if (idx < 34)      { hr = 0;        hc = idx;      }
        else if (idx < 68) { hr = 5;        hc = idx - 34; }
        else if (idx < 72) { hr = idx - 67; hc = 0;        }   // r = 1..4
        else               { hr = idx - 71; hc = 33;       }   // r = 1..4
        const int hg = byp*4 + hr - 1, wg = px0 + hc - 1;
        hinb = (hg >= 0 && hg < 256 && wg >= 0 && wg < 256);
        if (hinb) {
            const int po = hg*256 + wg;
            #pragma unroll
            for (int j = 0; j < 16; ++j) {
                const int c0 = hh*16 + j;           // p=0 half
                const int c1 = 32 + hh*16 + j;      // p=1 half
                hbb0 |= (__float_as_uint(xb[(size_t)c0*HW + po] + mb[c0]) >> 31) << j;
                hbb1 |= (__float_as_uint(xb[(size_t)c1*HW + po] + mb[c1]) >> 31) << j;
            }
        }
    }

    // ---- Interior loads: lane covers 4 px (pxg*4..+3) x 8 ch (chg*8..+7) of row w.
    const f32x4* xrow = (const f32x4*)(xb + (size_t)(chg*8)*HW + h0*256 + px0 + pxg*4);
    f32x4 v[8];
    #pragma unroll
    for (int i = 0; i < 8; ++i) v[i] = xrow[(size_t)i*(HW/4)];
    f32x4 m0 = *(const f32x4*)&mb[chg*8];
    f32x4 m1 = *(const f32x4*)&mb[chg*8 + 4];

    unsigned long long sb0, sb1, sb2, sb3;   // per-px sign words (named: no dyn indexing)
    bf16x8 pk[4];
    {
        unsigned int by[4];
        #pragma unroll
        for (int e = 0; e < 4; ++e) {
            unsigned int bb = 0;
            #pragma unroll
            for (int i = 0; i < 8; ++i) {
                float xv = v[i][e];
                float mm = (i < 4) ? m0[i] : m1[i-4];
                bb |= (__float_as_uint(xv + mm) >> 31) << i;
                pk[e][i] = (__bf16)xv;
            }
            by[e] = bb;
        }
        const int sh = chg*8;
        sb0 = ((unsigned long long)by[0]) << sh;
        sb1 = ((unsigned long long)by[1]) << sh;
        sb2 = ((unsigned long long)by[2]) << sh;
        sb3 = ((unsigned long long)by[3]) << sh;
    }
    // OR-tree over the 8 ch-groups (lane bits 3..5)
    #pragma unroll
    for (int m = 8; m <= 32; m <<= 1) {
        sb0 |= __shfl_xor(sb0, m);
        sb1 |= __shfl_xor(sb1, m);
        sb2 |= __shfl_xor(sb2, m);
        sb3 |= __shfl_xor(sb3, m);
    }

    // ---- bf16 x -> block-shared exchange buffer (row w), XOR-swizzled.
    #pragma unroll
    for (int e = 0; e < 4; ++e) {
        const int px = pxg*4 + e;
        *(bf16x8*)&xsl4[((w*8 + chg)*32 + (px ^ (chg & 7)))*8] = pk[e];
    }

    // ---- Interior sign planes: lane writes px = pxg*4 + (chg&3), 2 slots, row w+1.
    {
        const int e = chg & 3;
        unsigned long long mysb = (e == 0) ? sb0 : (e == 1) ? sb1 : (e == 2) ? sb2 : sb3;
        const int px = pxg*4 + e;
        const int sbase = (chg >> 2)*2;
        #pragma unroll
        for (int sp = 0; sp < 2; ++sp) {
            const int s = sbase + sp;
            unsigned int slice = (unsigned int)(mysb >> (s*16)) & 0xffffu;
            i32x4 dw;
            dw[0] = expand4(slice & 15);
            dw[1] = expand4((slice >> 4) & 15);
            dw[2] = expand4((slice >> 8) & 15);
            dw[3] = expand4((slice >> 12) & 15);
            *(i32x4*)&planes[(((w + 1)*4 + s)*34 + px + 1)*16] = dw;
        }
    }

    // ---- Halo plane writes. OOB pixels write zero bytes (exact zero padding).
    if (tid < 152) {
        const int hh = tid & 1;
        #pragma unroll
        for (int p = 0; p < 2; ++p) {
            i32x4 dw = (i32x4){0, 0, 0, 0};
            if (hinb) {
                const unsigned int bb = p ? hbb1 : hbb0;
                dw[0] = expand4(bb & 15);
                dw[1] = expand4((bb >> 4) & 15);
                dw[2] = expand4((bb >> 8) & 15);
                dw[3] = expand4((bb >> 12) & 15);
            }
            *(i32x4*)&planes[((hr*4 + (hh + 2*p))*34 + hc)*16] = dw;
        }
    }
    __syncthreads();   // the ONLY barrier: xsl4 + planes ready

    // ---- Expand all 9 taps' A-fragments ONCE (36 VGPR; amortized over 4 rows).
    const unsigned int* arow = (const unsigned int*)&Abits[(w*64 + l)*10];
    unsigned int ad[5];
    #pragma unroll
    for (int k = 0; k < 5; ++k) ad[k] = arow[k];
    i32x4 a9[9];
    #pragma unroll
    for (int t = 0; t < 9; ++t) {
        const unsigned int tb = (ad[t >> 1] >> ((t & 1)*16)) & 0xffffu;
        a9[t][0] = expand4(tb & 15);
        a9[t][1] = expand4((tb >> 4) & 15);
        a9[t][2] = expand4((tb >> 8) & 15);
        a9[t][3] = expand4((tb >> 12) & 15);
    }

    // ---- Phase C, r-outer, TRANSPOSED MFMAs (x-frag as A, w-frag as B):
    // D: col=lane&15=o, row=(lane>>4)*4+reg=px => lane holds 4 consecutive px
    // of ONE output channel -> dwordx4 stores; cons load hoisted (o r-invariant).
    const int o = w*16 + lr;                  // this lane's output channel
    const f32x4 c4 = *(const f32x4*)&cons[o*4];   // (sf, pb0, aP, pb1+skip_b)
    float* outo = out + (size_t)b*64*HW + (size_t)o*HW + px0 + lg*4;

    #pragma unroll
    for (int r = 0; r < 4; ++r) {
        // skip conv (4 bf16 MFMAs), xsl4 reads swizzled — operands SWAPPED
        f32x4 sk0 = (f32x4){0.f,0.f,0.f,0.f}, sk1 = (f32x4){0.f,0.f,0.f,0.f};
        {
            bf16x8 bx00 = *(const bf16x8*)&xsl4[((r*8 + lg)*32 + (lr ^ lg))*8];
            bf16x8 bx01 = *(const bf16x8*)&xsl4[((r*8 + 4 + lg)*32 + (lr ^ ((4 + lg) & 7)))*8];
            bf16x8 bx10 = *(const bf16x8*)&xsl4[((r*8 + lg)*32 + ((16 + lr) ^ lg))*8];
            bf16x8 bx11 = *(const bf16x8*)&xsl4[((r*8 + 4 + lg)*32 + ((16 + lr) ^ ((4 + lg) & 7)))*8];
            sk0 = __builtin_amdgcn_mfma_f32_16x16x32_bf16(bx00, sa0, sk0, 0, 0, 0);
            sk0 = __builtin_amdgcn_mfma_f32_16x16x32_bf16(bx01, sa1, sk0, 0, 0, 0);
            sk1 = __builtin_amdgcn_mfma_f32_16x16x32_bf16(bx10, sa0, sk1, 0, 0, 0);
            sk1 = __builtin_amdgcn_mfma_f32_16x16x32_bf16(bx11, sa1, sk1, 0, 0, 0);
        }
        // binary conv (18 i8 MFMAs) — operands SWAPPED
        i32x4 bacc0 = (i32x4){0,0,0,0}, bacc1 = (i32x4){0,0,0,0};
        #pragma unroll
        for (int t = 0; t < 9; ++t) {
            const int dr = t / 3, dc = t % 3;
            const int pbase = ((r*4 + lg)*34 + lr)*16 + dr*(4*34*16) + dc*16;
            i32x4 b0 = *(const i32x4*)&planes[pbase];
            i32x4 b1 = *(const i32x4*)&planes[pbase + 256];
            bacc0 = __builtin_amdgcn_mfma_i32_16x16x64_i8(b0, a9[t], bacc0, 0, 0, 0);
            bacc1 = __builtin_amdgcn_mfma_i32_16x16x64_i8(b1, a9[t], bacc1, 0, 0, 0);
        }
        // epilogue row r: 2 dwordx4 stores (4 consecutive px of channel o each)
        float* outp = outo + (size_t)(byp*4 + r)*256;
        f32x4 res0, res1;
        #pragma unroll
        for (int qi = 0; qi < 4; ++qi) {
            {
                float tv = fmaf(c4[0], (float)bacc0[qi], c4[1]);
                tv = fmaxf(tv, 0.f) + c4[2]*fminf(tv, 0.f);
                res0[qi] = tv + c4[3] + sk0[qi];
            }
            {
                float tv = fmaf(c4[0], (float)bacc1[qi], c4[1]);
                tv = fmaxf(tv, 0.f) + c4[2]*fminf(tv, 0.f);
                res1[qi] = tv + c4[3] + sk1[qi];
            }
        }
        *(f32x4*)&outp[0]  = res0;
        *(f32x4*)&outp[16] = res1;
    }
}

extern "C" void kernel_launch(void* const* d_in, const int* in_sizes, int n_in,
                              void* d_out, int out_size, void* d_ws, size_t ws_size,
                              hipStream_t stream) {
    const float* x      = (const float*)d_in[0];
    const float* mb     = (const float*)d_in[1];
    const float* weight = (const float*)d_in[2];
    const float* pb0    = (const float*)d_in[3];
    const float* pw     = (const float*)d_in[4];
    const float* pb1    = (const float*)d_in[5];
    const float* skw    = (const float*)d_in[6];
    const float* skb    = (const float*)d_in[7];
    float* out = (float*)d_out;

    char* ws = (char*)d_ws;
    unsigned short* abits  = (unsigned short*)ws;              // 5120 B
    unsigned short* swfrag = (unsigned short*)(ws + 5120);     // 8192 B
    float*          consg  = (float*)(ws + 13312);             // 1024 B (total 14336)

    hipLaunchKernelGGL(bq_prep_kernel, dim3(1), dim3(576), 0, stream,
                       weight, pb0, pw, pb1, skb, skw, abits, swfrag, consg);
    hipLaunchKernelGGL(bq_main_kernel, dim3(4096), dim3(256), 0, stream,
                       x, mb, abits, swfrag, consg, out);
}

// Round 22
// 67.295 us; speedup vs baseline: 1.1276x; 1.1276x over previous
//
#include <hip/hip_runtime.h>

// BinaryConv2dSkip1x1 forward, MI355X — wave-per-rt, row-major dispatch,
// swizzled exchange + interleaved epilogue (r20) + ballot-parallel prep.
// out = RPReLU( conv3x3( sign(x+mb), sf*sign(w), pad=1 ) ) + conv1x1(x, skip_w) + skip_b
//
// Round-22: r21's transposed epilogue REVERTED (it de-coalesced stores: 16B/lane
// to 64 different channel planes vs r20's 64B segments; 73.6->75.9 regression).
// Main kernel = r20 verbatim (73.6us best). New: prep kernel parallelized
// 1 block/576thr -> 64 blocks/64thr (one wave per output channel): lane=ch
// loads 9 CONTIGUOUS floats, per-tap sign word = one __ballot (64-bit), sabs
// via shfl reduce. Cuts ~4-6us of serial single-CU prep to ~1us.

#define HW (256*256)

typedef __bf16 bf16x8 __attribute__((ext_vector_type(8)));
typedef float  f32x4  __attribute__((ext_vector_type(4)));
typedef int    i32x4  __attribute__((ext_vector_type(4)));

// expand 4 sign bits -> 4 i8 bytes (+1 for bit=0, -1 for bit=1)
__device__ __forceinline__ int expand4(unsigned int nib) {
    unsigned int spread = (nib * 0x00204081u) & 0x01010101u;  // bit i -> byte i LSB
    return (int)(0x01010101u ^ (spread * 0xFEu));             // 0x01 or 0xFF per byte
}

// ---------------- prep kernel: 64 blocks x 64 threads (block = one out-ch o) ----------
__global__ void bq_prep_kernel(const float* __restrict__ weight,   // [64][64][3][3]
                               const float* __restrict__ pr_bias0,
                               const float* __restrict__ prelu_w,
                               const float* __restrict__ pr_bias1,
                               const float* __restrict__ skip_b,
                               const float* __restrict__ skipw,    // [64][64]
                               unsigned short* __restrict__ abits, // [4rt][64 lane][10] u16
                               unsigned short* __restrict__ swfrag,// [4rt][2p][64 lane][8] bf16
                               float* __restrict__ consg) {        // [64][4]
    const int o  = blockIdx.x;      // 0..63
    const int ch = threadIdx.x;     // 0..63 (lane)
    const int m = o & 15, rt = o >> 4;

    // lane=ch loads its 9 taps CONTIGUOUSLY (36 B)
    float wv[9];
    const float* wp = weight + (size_t)(o*64 + ch)*9;
    #pragma unroll
    for (int t = 0; t < 9; ++t) wv[t] = wp[t];

    float sabs = 0.f;
    #pragma unroll
    for (int t = 0; t < 9; ++t) sabs += fabsf(wv[t]);

    // per-tap 64-ch sign word in ONE ballot; lanes 0..3 write the 4 u16 groups.
    // abits[(rt*64 + m + 16*g)*10 + t] bit j = sign(w[o][g*16+j][t])  (matches main)
    #pragma unroll
    for (int t = 0; t < 9; ++t) {
        unsigned long long word = __ballot(wv[t] < 0.f);
        if (ch < 4)
            abits[(rt*64 + m + 16*ch)*10 + t] =
                (unsigned short)((word >> (16*ch)) & 0xffffu);
    }

    // wave-reduce sabs -> sf
    #pragma unroll
    for (int mm = 1; mm < 64; mm <<= 1) sabs += __shfl_xor(sabs, mm);
    if (ch == 0) {
        float sf = sabs / 576.f;
        consg[o*4 + 0] = sf;
        consg[o*4 + 1] = pr_bias0[o];
        consg[o*4 + 2] = prelu_w[o];
        consg[o*4 + 3] = pr_bias1[o] + skip_b[o];
    }

    // skip-weight fragment: lane=ch writes one bf16.
    // ch = p*32 + gg*8 + i  ->  swfrag[((rt*2+p)*64 + (m+16*gg))*8 + i]
    {
        const int p = ch >> 5, gg = (ch >> 3) & 3, i = ch & 7;
        swfrag[((rt*2 + p)*64 + (m + 16*gg))*8 + i] =
            __builtin_bit_cast(unsigned short, (__bf16)skipw[o*64 + ch]);
    }
}

// ---------------- main kernel: tile 32 px x 4 rows, 256 threads (r20 verbatim) --------
__global__ __launch_bounds__(256, 4)
void bq_main_kernel(const float* __restrict__ x,        // [8][64][256][256]
                    const float* __restrict__ mb,       // [64]
                    const unsigned short* __restrict__ abits_g,
                    const unsigned short* __restrict__ swfrag,
                    const float* __restrict__ consg,
                    float* __restrict__ out) {
    __shared__ __align__(16) char planes[6*4*34*16];        // 13056 B
    __shared__ __align__(16) unsigned short xsl4[4*8*32*8]; // 16384 B [row][slot][px^](8)
    __shared__ __align__(16) unsigned short Abits[4*64*10]; // 5120 B
    __shared__ __align__(16) float cons[64*4];              // 1024 B => 35584 B total

    const int tid = threadIdx.x;
    const int l = tid & 63, w = tid >> 6;   // wave w: loads row w, computes rt=w
    const int pxg = l & 7,  chg = l >> 3;   // 4-px group / 8-ch group
    const int lg = l >> 4,  lr = l & 15;

    // XCD swizzle (r18): one batch image per XCD; within an XCD consecutive
    // launches walk COLUMNS (bxp) fastest -> 8 temporally-adjacent blocks cover
    // contiguous 1KB channel-rows (DRAM page locality; halos L2-hot).
    const int id  = blockIdx.x;                 // 0..4095
    const int vid = (id & 7)*512 + (id >> 3);   // 512 consecutive vids per XCD
    const int bxp = vid & 7;                    // 0..7   (fastest: column strip)
    const int byp = (vid >> 3) & 63;            // 0..63  (4-row strip)
    const int b   = vid >> 9;                   // 0..7   (one image per XCD)

    const int h0 = byp*4 + w, px0 = bxp*32;
    const float* xb = x + (size_t)b * 64 * HW;

    for (int i = tid; i < 1280; i += 256)
        ((unsigned int*)Abits)[i] = ((const unsigned int*)abits_g)[i];
    if (tid < 64) ((f32x4*)cons)[tid] = ((const f32x4*)consg)[tid];

    // Skip-weight A-fragments for this wave's rt (=w): 2 global 16B loads, hoisted.
    const bf16x8 sa0 = *(const bf16x8*)&swfrag[((w*2 + 0)*64 + l)*8];
    const bf16x8 sa1 = *(const bf16x8*)&swfrag[((w*2 + 1)*64 + l)*8];

    // ---- Halo sign bits EARLY: 76 px x 2 ch-halves = 152 jobs; results = 2 regs.
    int hr = 0, hc = 0;
    bool hinb = false;
    unsigned int hbb0 = 0, hbb1 = 0;
    if (tid < 152) {
        const int idx = tid >> 1, hh = tid & 1;
        if (idx < 34)      { hr = 0;        hc = idx;      }
        else if (idx < 68) { hr = 5;        hc = idx - 34; }
        else if (idx < 72) { hr = idx - 67; hc = 0;        }   // r = 1..4
        else               { hr = idx - 71; hc = 33;       }   // r = 1..4
        const int hg = byp*4 + hr - 1, wg = px0 + hc - 1;
        hinb = (hg >= 0 && hg < 256 && wg >= 0 && wg < 256);
        if (hinb) {
            const int po = hg*256 + wg;
            #pragma unroll
            for (int j = 0; j < 16; ++j) {
                const int c0 = hh*16 + j;           // p=0 half
                const int c1 = 32 + hh*16 + j;      // p=1 half
                hbb0 |= (__float_as_uint(xb[(size_t)c0*HW + po] + mb[c0]) >> 31) << j;
                hbb1 |= (__float_as_uint(xb[(size_t)c1*HW + po] + mb[c1]) >> 31) << j;
            }
        }
    }

    // ---- Interior loads: lane covers 4 px (pxg*4..+3) x 8 ch (chg*8..+7) of row w.
    const f32x4* xrow = (const f32x4*)(xb + (size_t)(chg*8)*HW + h0*256 + px0 + pxg*4);
    f32x4 v[8];
    #pragma unroll
    for (int i = 0; i < 8; ++i) v[i] = xrow[(size_t)i*(HW/4)];
    f32x4 m0 = *(const f32x4*)&mb[chg*8];
    f32x4 m1 = *(const f32x4*)&mb[chg*8 + 4];

    unsigned long long sb0, sb1, sb2, sb3;   // per-px sign words (named: no dyn indexing)
    bf16x8 pk[4];
    {
        unsigned int by[4];
        #pragma unroll
        for (int e = 0; e < 4; ++e) {
            unsigned int bb = 0;
            #pragma unroll
            for (int i = 0; i < 8; ++i) {
                float xv = v[i][e];
                float mm = (i < 4) ? m0[i] : m1[i-4];
                bb |= (__float_as_uint(xv + mm) >> 31) << i;
                pk[e][i] = (__bf16)xv;
            }
            by[e] = bb;
        }
        const int sh = chg*8;
        sb0 = ((unsigned long long)by[0]) << sh;
        sb1 = ((unsigned long long)by[1]) << sh;
        sb2 = ((unsigned long long)by[2]) << sh;
        sb3 = ((unsigned long long)by[3]) << sh;
    }
    // OR-tree over the 8 ch-groups (lane bits 3..5)
    #pragma unroll
    for (int m = 8; m <= 32; m <<= 1) {
        sb0 |= __shfl_xor(sb0, m);
        sb1 |= __shfl_xor(sb1, m);
        sb2 |= __shfl_xor(sb2, m);
        sb3 |= __shfl_xor(sb3, m);
    }

    // ---- bf16 x -> block-shared exchange buffer (row w), XOR-swizzled:
    // 16B-unit index u = slot*32 + (px ^ (slot&7)).
    #pragma unroll
    for (int e = 0; e < 4; ++e) {
        const int px = pxg*4 + e;
        *(bf16x8*)&xsl4[((w*8 + chg)*32 + (px ^ (chg & 7)))*8] = pk[e];
    }

    // ---- Interior sign planes: lane writes px = pxg*4 + (chg&3), 2 slots, row w+1.
    {
        const int e = chg & 3;
        unsigned long long mysb = (e == 0) ? sb0 : (e == 1) ? sb1 : (e == 2) ? sb2 : sb3;
        const int px = pxg*4 + e;
        const int sbase = (chg >> 2)*2;
        #pragma unroll
        for (int sp = 0; sp < 2; ++sp) {
            const int s = sbase + sp;
            unsigned int slice = (unsigned int)(mysb >> (s*16)) & 0xffffu;
            i32x4 dw;
            dw[0] = expand4(slice & 15);
            dw[1] = expand4((slice >> 4) & 15);
            dw[2] = expand4((slice >> 8) & 15);
            dw[3] = expand4((slice >> 12) & 15);
            *(i32x4*)&planes[(((w + 1)*4 + s)*34 + px + 1)*16] = dw;
        }
    }

    // ---- Halo plane writes. OOB pixels write zero bytes (exact zero padding).
    if (tid < 152) {
        const int hh = tid & 1;
        #pragma unroll
        for (int p = 0; p < 2; ++p) {
            i32x4 dw = (i32x4){0, 0, 0, 0};
            if (hinb) {
                const unsigned int bb = p ? hbb1 : hbb0;
                dw[0] = expand4(bb & 15);
                dw[1] = expand4((bb >> 4) & 15);
                dw[2] = expand4((bb >> 8) & 15);
                dw[3] = expand4((bb >> 12) & 15);
            }
            *(i32x4*)&planes[((hr*4 + (hh + 2*p))*34 + hc)*16] = dw;
        }
    }
    __syncthreads();   // the ONLY barrier: xsl4 + planes ready

    // ---- Expand all 9 taps' A-fragments ONCE (36 VGPR; amortized over 4 rows).
    const unsigned int* arow = (const unsigned int*)&Abits[(w*64 + l)*10];
    unsigned int ad[5];
    #pragma unroll
    for (int k = 0; k < 5; ++k) ad[k] = arow[k];
    i32x4 a9[9];
    #pragma unroll
    for (int t = 0; t < 9; ++t) {
        const unsigned int tb = (ad[t >> 1] >> ((t & 1)*16)) & 0xffffu;
        a9[t][0] = expand4(tb & 15);
        a9[t][1] = expand4((tb >> 4) & 15);
        a9[t][2] = expand4((tb >> 8) & 15);
        a9[t][3] = expand4((tb >> 12) & 15);
    }

    // ---- Phase C, r-outer: per row r do skip-MFMA + binary-MFMA + epilogue.
    float* outb = out + (size_t)b*64*HW;
    #pragma unroll
    for (int r = 0; r < 4; ++r) {
        // skip conv (4 bf16 MFMAs), xsl4 reads swizzled
        f32x4 sk0 = (f32x4){0.f,0.f,0.f,0.f}, sk1 = (f32x4){0.f,0.f,0.f,0.f};
        {
            bf16x8 bx00 = *(const bf16x8*)&xsl4[((r*8 + lg)*32 + (lr ^ lg))*8];
            bf16x8 bx01 = *(const bf16x8*)&xsl4[((r*8 + 4 + lg)*32 + (lr ^ ((4 + lg) & 7)))*8];
            bf16x8 bx10 = *(const bf16x8*)&xsl4[((r*8 + lg)*32 + ((16 + lr) ^ lg))*8];
            bf16x8 bx11 = *(const bf16x8*)&xsl4[((r*8 + 4 + lg)*32 + ((16 + lr) ^ ((4 + lg) & 7)))*8];
            sk0 = __builtin_amdgcn_mfma_f32_16x16x32_bf16(sa0, bx00, sk0, 0, 0, 0);
            sk0 = __builtin_amdgcn_mfma_f32_16x16x32_bf16(sa1, bx01, sk0, 0, 0, 0);
            sk1 = __builtin_amdgcn_mfma_f32_16x16x32_bf16(sa0, bx10, sk1, 0, 0, 0);
            sk1 = __builtin_amdgcn_mfma_f32_16x16x32_bf16(sa1, bx11, sk1, 0, 0, 0);
        }
        // binary conv (18 i8 MFMAs)
        i32x4 bacc0 = (i32x4){0,0,0,0}, bacc1 = (i32x4){0,0,0,0};
        #pragma unroll
        for (int t = 0; t < 9; ++t) {
            const int dr = t / 3, dc = t % 3;
            const int pbase = ((r*4 + lg)*34 + lr)*16 + dr*(4*34*16) + dc*16;
            i32x4 b0 = *(const i32x4*)&planes[pbase];
            i32x4 b1 = *(const i32x4*)&planes[pbase + 256];
            bacc0 = __builtin_amdgcn_mfma_i32_16x16x64_i8(a9[t], b0, bacc0, 0, 0, 0);
            bacc1 = __builtin_amdgcn_mfma_i32_16x16x64_i8(a9[t], b1, bacc1, 0, 0, 0);
        }
        // epilogue row r: wave w writes o in [w*16, w*16+16)
        float* outp = outb + (byp*4 + r)*256 + px0;
        #pragma unroll
        for (int qi = 0; qi < 4; ++qi) {
            const int o = w*16 + lg*4 + qi;
            f32x4 c4 = *(const f32x4*)&cons[o*4];   // (sf, pb0, aP, pb1+skip_b)
            {
                float tv = fmaf(c4[0], (float)bacc0[qi], c4[1]);
                tv = fmaxf(tv, 0.f) + c4[2]*fminf(tv, 0.f);
                outp[(size_t)o*HW + lr] = tv + c4[3] + sk0[qi];
            }
            {
                float tv = fmaf(c4[0], (float)bacc1[qi], c4[1]);
                tv = fmaxf(tv, 0.f) + c4[2]*fminf(tv, 0.f);
                outp[(size_t)o*HW + 16 + lr] = tv + c4[3] + sk1[qi];
            }
        }
    }
}

extern "C" void kernel_launch(void* const* d_in, const int* in_sizes, int n_in,
                              void* d_out, int out_size, void* d_ws, size_t ws_size,
                              hipStream_t stream) {
    const float* x      = (const float*)d_in[0];
    const float* mb     = (const float*)d_in[1];
    const float* weight = (const float*)d_in[2];
    const float* pb0    = (const float*)d_in[3];
    const float* pw     = (const float*)d_in[4];
    const float* pb1    = (const float*)d_in[5];
    const float* skw    = (const float*)d_in[6];
    const float* skb    = (const float*)d_in[7];
    float* out = (float*)d_out;

    char* ws = (char*)d_ws;
    unsigned short* abits  = (unsigned short*)ws;              // 5120 B
    unsigned short* swfrag = (unsigned short*)(ws + 5120);     // 8192 B
    float*          consg  = (float*)(ws + 13312);             // 1024 B (total 14336)

    hipLaunchKernelGGL(bq_prep_kernel, dim3(64), dim3(64), 0, stream,
                       weight, pb0, pw, pb1, skb, skw, abits, swfrag, consg);
    hipLaunchKernelGGL(bq_main_kernel, dim3(4096), dim3(256), 0, stream,
                       x, mb, abits, swfrag, consg, out);
}

// Round 23
// 66.376 us; speedup vs baseline: 1.1432x; 1.0138x over previous
//
#include <hip/hip_runtime.h>

// BinaryConv2dSkip1x1 forward, MI355X — wave-per-rt, row-major dispatch,
// swizzled exchange + interleaved epilogue + ballot prep + NT stores.
// out = RPReLU( conv3x3( sign(x+mb), sf*sign(w), pad=1 ) ) + conv1x1(x, skip_w) + skip_b
//
// Round-23 (base r22, 67.3us): epilogue stores made NON-TEMPORAL
// (__builtin_nontemporal_store -> 'nt' flag). The 131MB output is written once
// and never re-read, but was flowing through L2/L3 and evicting x (134MB,
// L3-fits) — FETCH=67MB shows half of x re-fetched from HBM. NT stores bypass
// the caches so x + halo lines stay resident; read-side HBM traffic drops.

#define HW (256*256)

typedef __bf16 bf16x8 __attribute__((ext_vector_type(8)));
typedef float  f32x4  __attribute__((ext_vector_type(4)));
typedef int    i32x4  __attribute__((ext_vector_type(4)));

// expand 4 sign bits -> 4 i8 bytes (+1 for bit=0, -1 for bit=1)
__device__ __forceinline__ int expand4(unsigned int nib) {
    unsigned int spread = (nib * 0x00204081u) & 0x01010101u;  // bit i -> byte i LSB
    return (int)(0x01010101u ^ (spread * 0xFEu));             // 0x01 or 0xFF per byte
}

// ---------------- prep kernel: 64 blocks x 64 threads (block = one out-ch o) ----------
__global__ void bq_prep_kernel(const float* __restrict__ weight,   // [64][64][3][3]
                               const float* __restrict__ pr_bias0,
                               const float* __restrict__ prelu_w,
                               const float* __restrict__ pr_bias1,
                               const float* __restrict__ skip_b,
                               const float* __restrict__ skipw,    // [64][64]
                               unsigned short* __restrict__ abits, // [4rt][64 lane][10] u16
                               unsigned short* __restrict__ swfrag,// [4rt][2p][64 lane][8] bf16
                               float* __restrict__ consg) {        // [64][4]
    const int o  = blockIdx.x;      // 0..63
    const int ch = threadIdx.x;     // 0..63 (lane)
    const int m = o & 15, rt = o >> 4;

    // lane=ch loads its 9 taps CONTIGUOUSLY (36 B)
    float wv[9];
    const float* wp = weight + (size_t)(o*64 + ch)*9;
    #pragma unroll
    for (int t = 0; t < 9; ++t) wv[t] = wp[t];

    float sabs = 0.f;
    #pragma unroll
    for (int t = 0; t < 9; ++t) sabs += fabsf(wv[t]);

    // per-tap 64-ch sign word in ONE ballot; lanes 0..3 write the 4 u16 groups.
    #pragma unroll
    for (int t = 0; t < 9; ++t) {
        unsigned long long word = __ballot(wv[t] < 0.f);
        if (ch < 4)
            abits[(rt*64 + m + 16*ch)*10 + t] =
                (unsigned short)((word >> (16*ch)) & 0xffffu);
    }

    // wave-reduce sabs -> sf
    #pragma unroll
    for (int mm = 1; mm < 64; mm <<= 1) sabs += __shfl_xor(sabs, mm);
    if (ch == 0) {
        float sf = sabs / 576.f;
        consg[o*4 + 0] = sf;
        consg[o*4 + 1] = pr_bias0[o];
        consg[o*4 + 2] = prelu_w[o];
        consg[o*4 + 3] = pr_bias1[o] + skip_b[o];
    }

    // skip-weight fragment: lane=ch writes one bf16.
    {
        const int p = ch >> 5, gg = (ch >> 3) & 3, i = ch & 7;
        swfrag[((rt*2 + p)*64 + (m + 16*gg))*8 + i] =
            __builtin_bit_cast(unsigned short, (__bf16)skipw[o*64 + ch]);
    }
}

// ---------------- main kernel: tile 32 px x 4 rows, 256 threads ------------------------
__global__ __launch_bounds__(256, 4)
void bq_main_kernel(const float* __restrict__ x,        // [8][64][256][256]
                    const float* __restrict__ mb,       // [64]
                    const unsigned short* __restrict__ abits_g,
                    const unsigned short* __restrict__ swfrag,
                    const float* __restrict__ consg,
                    float* __restrict__ out) {
    __shared__ __align__(16) char planes[6*4*34*16];        // 13056 B
    __shared__ __align__(16) unsigned short xsl4[4*8*32*8]; // 16384 B [row][slot][px^](8)
    __shared__ __align__(16) unsigned short Abits[4*64*10]; // 5120 B
    __shared__ __align__(16) float cons[64*4];              // 1024 B => 35584 B total

    const int tid = threadIdx.x;
    const int l = tid & 63, w = tid >> 6;   // wave w: loads row w, computes rt=w
    const int pxg = l & 7,  chg = l >> 3;   // 4-px group / 8-ch group
    const int lg = l >> 4,  lr = l & 15;

    // XCD swizzle (r18): one batch image per XCD; within an XCD consecutive
    // launches walk COLUMNS (bxp) fastest -> DRAM page locality; halos L2-hot.
    const int id  = blockIdx.x;                 // 0..4095
    const int vid = (id & 7)*512 + (id >> 3);   // 512 consecutive vids per XCD
    const int bxp = vid & 7;                    // 0..7   (fastest: column strip)
    const int byp = (vid >> 3) & 63;            // 0..63  (4-row strip)
    const int b   = vid >> 9;                   // 0..7   (one image per XCD)

    const int h0 = byp*4 + w, px0 = bxp*32;
    const float* xb = x + (size_t)b * 64 * HW;

    for (int i = tid; i < 1280; i += 256)
        ((unsigned int*)Abits)[i] = ((const unsigned int*)abits_g)[i];
    if (tid < 64) ((f32x4*)cons)[tid] = ((const f32x4*)consg)[tid];

    // Skip-weight A-fragments for this wave's rt (=w): 2 global 16B loads, hoisted.
    const bf16x8 sa0 = *(const bf16x8*)&swfrag[((w*2 + 0)*64 + l)*8];
    const bf16x8 sa1 = *(const bf16x8*)&swfrag[((w*2 + 1)*64 + l)*8];

    // ---- Halo sign bits EARLY: 76 px x 2 ch-halves = 152 jobs; results = 2 regs.
    int hr = 0, hc = 0;
    bool hinb = false;
    unsigned int hbb0 = 0, hbb1 = 0;
    if (tid < 152) {
        const int idx = tid >> 1, hh = tid & 1;
        if (idx < 34)      { hr = 0;        hc = idx;      }
        else if (idx < 68) { hr = 5;        hc = idx - 34; }
        else if (idx < 72) { hr = idx - 67; hc = 0;        }   // r = 1..4
        else               { hr = idx - 71; hc = 33;       }   // r = 1..4
        const int hg = byp*4 + hr - 1, wg = px0 + hc - 1;
        hinb = (hg >= 0 && hg < 256 && wg >= 0 && wg < 256);
        if (hinb) {
            const int po = hg*256 + wg;
            #pragma unroll
            for (int j = 0; j < 16; ++j) {
                const int c0 = hh*16 + j;           // p=0 half
                const int c1 = 32 + hh*16 + j;      // p=1 half
                hbb0 |= (__float_as_uint(xb[(size_t)c0*HW + po] + mb[c0]) >> 31) << j;
                hbb1 |= (__float_as_uint(xb[(size_t)c1*HW + po] + mb[c1]) >> 31) << j;
            }
        }
    }

    // ---- Interior loads: lane covers 4 px (pxg*4..+3) x 8 ch (chg*8..+7) of row w.
    const f32x4* xrow = (const f32x4*)(xb + (size_t)(chg*8)*HW + h0*256 + px0 + pxg*4);
    f32x4 v[8];
    #pragma unroll
    for (int i = 0; i < 8; ++i) v[i] = xrow[(size_t)i*(HW/4)];
    f32x4 m0 = *(const f32x4*)&mb[chg*8];
    f32x4 m1 = *(const f32x4*)&mb[chg*8 + 4];

    unsigned long long sb0, sb1, sb2, sb3;   // per-px sign words (named: no dyn indexing)
    bf16x8 pk[4];
    {
        unsigned int by[4];
        #pragma unroll
        for (int e = 0; e < 4; ++e) {
            unsigned int bb = 0;
            #pragma unroll
            for (int i = 0; i < 8; ++i) {
                float xv = v[i][e];
                float mm = (i < 4) ? m0[i] : m1[i-4];
                bb |= (__float_as_uint(xv + mm) >> 31) << i;
                pk[e][i] = (__bf16)xv;
            }
            by[e] = bb;
        }
        const int sh = chg*8;
        sb0 = ((unsigned long long)by[0]) << sh;
        sb1 = ((unsigned long long)by[1]) << sh;
        sb2 = ((unsigned long long)by[2]) << sh;
        sb3 = ((unsigned long long)by[3]) << sh;
    }
    // OR-tree over the 8 ch-groups (lane bits 3..5)
    #pragma unroll
    for (int m = 8; m <= 32; m <<= 1) {
        sb0 |= __shfl_xor(sb0, m);
        sb1 |= __shfl_xor(sb1, m);
        sb2 |= __shfl_xor(sb2, m);
        sb3 |= __shfl_xor(sb3, m);
    }

    // ---- bf16 x -> block-shared exchange buffer (row w), XOR-swizzled.
    #pragma unroll
    for (int e = 0; e < 4; ++e) {
        const int px = pxg*4 + e;
        *(bf16x8*)&xsl4[((w*8 + chg)*32 + (px ^ (chg & 7)))*8] = pk[e];
    }

    // ---- Interior sign planes: lane writes px = pxg*4 + (chg&3), 2 slots, row w+1.
    {
        const int e = chg & 3;
        unsigned long long mysb = (e == 0) ? sb0 : (e == 1) ? sb1 : (e == 2) ? sb2 : sb3;
        const int px = pxg*4 + e;
        const int sbase = (chg >> 2)*2;
        #pragma unroll
        for (int sp = 0; sp < 2; ++sp) {
            const int s = sbase + sp;
            unsigned int slice = (unsigned int)(mysb >> (s*16)) & 0xffffu;
            i32x4 dw;
            dw[0] = expand4(slice & 15);
            dw[1] = expand4((slice >> 4) & 15);
            dw[2] = expand4((slice >> 8) & 15);
            dw[3] = expand4((slice >> 12) & 15);
            *(i32x4*)&planes[(((w + 1)*4 + s)*34 + px + 1)*16] = dw;
        }
    }

    // ---- Halo plane writes. OOB pixels write zero bytes (exact zero padding).
    if (tid < 152) {
        const int hh = tid & 1;
        #pragma unroll
        for (int p = 0; p < 2; ++p) {
            i32x4 dw = (i32x4){0, 0, 0, 0};
            if (hinb) {
                const unsigned int bb = p ? hbb1 : hbb0;
                dw[0] = expand4(bb & 15);
                dw[1] = expand4((bb >> 4) & 15);
                dw[2] = expand4((bb >> 8) & 15);
                dw[3] = expand4((bb >> 12) & 15);
            }
            *(i32x4*)&planes[((hr*4 + (hh + 2*p))*34 + hc)*16] = dw;
        }
    }
    __syncthreads();   // the ONLY barrier: xsl4 + planes ready

    // ---- Expand all 9 taps' A-fragments ONCE (36 VGPR; amortized over 4 rows).
    const unsigned int* arow = (const unsigned int*)&Abits[(w*64 + l)*10];
    unsigned int ad[5];
    #pragma unroll
    for (int k = 0; k < 5; ++k) ad[k] = arow[k];
    i32x4 a9[9];
    #pragma unroll
    for (int t = 0; t < 9; ++t) {
        const unsigned int tb = (ad[t >> 1] >> ((t & 1)*16)) & 0xffffu;
        a9[t][0] = expand4(tb & 15);
        a9[t][1] = expand4((tb >> 4) & 15);
        a9[t][2] = expand4((tb >> 8) & 15);
        a9[t][3] = expand4((tb >> 12) & 15);
    }

    // ---- Phase C, r-outer: per row r do skip-MFMA + binary-MFMA + epilogue.
    float* outb = out + (size_t)b*64*HW;
    #pragma unroll
    for (int r = 0; r < 4; ++r) {
        // skip conv (4 bf16 MFMAs), xsl4 reads swizzled
        f32x4 sk0 = (f32x4){0.f,0.f,0.f,0.f}, sk1 = (f32x4){0.f,0.f,0.f,0.f};
        {
            bf16x8 bx00 = *(const bf16x8*)&xsl4[((r*8 + lg)*32 + (lr ^ lg))*8];
            bf16x8 bx01 = *(const bf16x8*)&xsl4[((r*8 + 4 + lg)*32 + (lr ^ ((4 + lg) & 7)))*8];
            bf16x8 bx10 = *(const bf16x8*)&xsl4[((r*8 + lg)*32 + ((16 + lr) ^ lg))*8];
            bf16x8 bx11 = *(const bf16x8*)&xsl4[((r*8 + 4 + lg)*32 + ((16 + lr) ^ ((4 + lg) & 7)))*8];
            sk0 = __builtin_amdgcn_mfma_f32_16x16x32_bf16(sa0, bx00, sk0, 0, 0, 0);
            sk0 = __builtin_amdgcn_mfma_f32_16x16x32_bf16(sa1, bx01, sk0, 0, 0, 0);
            sk1 = __builtin_amdgcn_mfma_f32_16x16x32_bf16(sa0, bx10, sk1, 0, 0, 0);
            sk1 = __builtin_amdgcn_mfma_f32_16x16x32_bf16(sa1, bx11, sk1, 0, 0, 0);
        }
        // binary conv (18 i8 MFMAs)
        i32x4 bacc0 = (i32x4){0,0,0,0}, bacc1 = (i32x4){0,0,0,0};
        #pragma unroll
        for (int t = 0; t < 9; ++t) {
            const int dr = t / 3, dc = t % 3;
            const int pbase = ((r*4 + lg)*34 + lr)*16 + dr*(4*34*16) + dc*16;
            i32x4 b0 = *(const i32x4*)&planes[pbase];
            i32x4 b1 = *(const i32x4*)&planes[pbase + 256];
            bacc0 = __builtin_amdgcn_mfma_i32_16x16x64_i8(a9[t], b0, bacc0, 0, 0, 0);
            bacc1 = __builtin_amdgcn_mfma_i32_16x16x64_i8(a9[t], b1, bacc1, 0, 0, 0);
        }
        // epilogue row r: wave w writes o in [w*16, w*16+16) — NON-TEMPORAL stores
        float* outp = outb + (byp*4 + r)*256 + px0;
        #pragma unroll
        for (int qi = 0; qi < 4; ++qi) {
            const int o = w*16 + lg*4 + qi;
            f32x4 c4 = *(const f32x4*)&cons[o*4];   // (sf, pb0, aP, pb1+skip_b)
            {
                float tv = fmaf(c4[0], (float)bacc0[qi], c4[1]);
                tv = fmaxf(tv, 0.f) + c4[2]*fminf(tv, 0.f);
                __builtin_nontemporal_store(tv + c4[3] + sk0[qi],
                                            &outp[(size_t)o*HW + lr]);
            }
            {
                float tv = fmaf(c4[0], (float)bacc1[qi], c4[1]);
                tv = fmaxf(tv, 0.f) + c4[2]*fminf(tv, 0.f);
                __builtin_nontemporal_store(tv + c4[3] + sk1[qi],
                                            &outp[(size_t)o*HW + 16 + lr]);
            }
        }
    }
}

extern "C" void kernel_launch(void* const* d_in, const int* in_sizes, int n_in,
                              void* d_out, int out_size, void* d_ws, size_t ws_size,
                              hipStream_t stream) {
    const float* x      = (const float*)d_in[0];
    const float* mb     = (const float*)d_in[1];
    const float* weight = (const float*)d_in[2];
    const float* pb0    = (const float*)d_in[3];
    const float* pw     = (const float*)d_in[4];
    const float* pb1    = (const float*)d_in[5];
    const float* skw    = (const float*)d_in[6];
    const float* skb    = (const float*)d_in[7];
    float* out = (float*)d_out;

    char* ws = (char*)d_ws;
    unsigned short* abits  = (unsigned short*)ws;              // 5120 B
    unsigned short* swfrag = (unsigned short*)(ws + 5120);     // 8192 B
    float*          consg  = (float*)(ws + 13312);             // 1024 B (total 14336)

    hipLaunchKernelGGL(bq_prep_kernel, dim3(64), dim3(64), 0, stream,
                       weight, pb0, pw, pb1, skb, skw, abits, swfrag, consg);
    hipLaunchKernelGGL(bq_main_kernel, dim3(4096), dim3(256), 0, stream,
                       x, mb, abits, swfrag, consg, out);
}